// Round 16
// baseline (183.961 us; speedup 1.0000x reference)
//
#include <hip/hip_runtime.h>
#include <hip/hip_bf16.h>

#define NN 100000
#define NE 1600000
#define FIN 512
#define FH 32
#define FC 16
#define NCB2 ((NE / 8 + 255) / 256)         // 782 fill blocks (8 edges/thread)
#define M_SL 32                             // edge slices
#define SLICE (NE / M_SL)                   // 50000 edges/slice
#define QSL (SLICE / 4)                     // 12500 quads/slice
#define PSZ 32768                           // nodes per pass (byte-packed 32 KB LDS)
#define NP ((NN + PSZ - 1) / PSZ)           // 4 passes
#define NHB (M_SL * NP)                     // 128 hist blocks
#define NGB1 ((NN + 63) / 64)               // 1563 MFMA gemm blocks
#define XW (NN / 4)                         // 25000 ghist words per slice
#define XSB ((XW + 255) / 256)              // 98 xscan blocks
#define SOS_NB 98                           // off-scan blocks (1024 nodes each)
#define SCALE_B ((NN * 8 + 1023) / 1024)    // 782 scale blocks (uint2 lanes)

typedef __attribute__((ext_vector_type(8))) short bf16x8;
typedef __attribute__((ext_vector_type(4))) float f32x4;

__device__ inline unsigned short f2bf(float f) {
    unsigned u = __float_as_uint(f);
    return (unsigned short)((u + 0x7FFFu + ((u >> 16) & 1u)) >> 16);  // RNE
}
__device__ inline float bf2f(unsigned short u) {
    return __uint_as_float(((unsigned)u) << 16);
}
__device__ inline unsigned pk2bf(float a, float b) {  // packed 2xbf16 via v_cvt_pk_bf16_f32
    __hip_bfloat162 p = __float22bfloat162_rn(make_float2(a, b));
    union { __hip_bfloat162 h; unsigned u; } c;
    c.h = p;
    return c.u;
}

// ---------------- prep: W1 -> bf16, pre-swizzled to B-fragment order ----------------

__global__ __launch_bounds__(256) void k_prep(const float* __restrict__ W1,
                                              unsigned short* __restrict__ wbuf) {
    for (int idx = threadIdx.x; idx < 16 * 2 * 64; idx += 256) {
        int s = idx >> 7;
        int t = (idx >> 6) & 1;
        int l = idx & 63;
        int k0 = s * 32 + (l >> 4) * 8;
        int c = t * 16 + (l & 15);
        bf16x8 w;
#pragma unroll
        for (int i = 0; i < 8; ++i) w[i] = (short)f2bf(W1[(size_t)(k0 + i) * FH + c]);
        *(bf16x8*)(wbuf + (size_t)idx * 8) = w;
    }
}

// ---------------- fused: MFMA GEMM1 (bf16 permuted out)  +  byte-packed LDS hist ----------------
// h1p layout: row = 16 u32 words; word w packs (col w, col w+16) as 2xbf16.

__global__ __launch_bounds__(256) void k_hist_gemm1(const int* __restrict__ col,
                                                    unsigned char* __restrict__ ghist,
                                                    unsigned char* __restrict__ rank,
                                                    const float* __restrict__ x,
                                                    const unsigned short* __restrict__ wbuf,
                                                    unsigned* __restrict__ h1p) {
    __shared__ int sh[PSZ / 4];  // 32 KB; gemm path reuses as bf16 W store

    if (blockIdx.x >= NGB1) {
        int hb = blockIdx.x - NGB1;
        int p = hb / M_SL;
        int m = hb % M_SL;
        int base = p * PSZ;
        int nb = min(PSZ, NN - base);
        int nw = (nb + 3) >> 2;
        unsigned* shw = (unsigned*)sh;
        for (int i = threadIdx.x; i < nw; i += 256) shw[i] = 0u;
        __syncthreads();
        const int4* c4p = (const int4*)(col + m * SLICE);
        for (int it = 0; it < (QSL + 255) / 256; ++it) {
            int q = it * 256 + threadIdx.x;
            if (q < QSL) {
                int4 c4 = c4p[q];
                int e = m * SLICE + q * 4;
                int cc[4] = {c4.x, c4.y, c4.z, c4.w};
#pragma unroll
                for (int u = 0; u < 4; ++u) {
                    int d = cc[u] - base;
                    if ((unsigned)d < (unsigned)nb) {
                        int sft = 8 * (d & 3);
                        unsigned old = atomicAdd(&shw[d >> 2], 1u << sft);
                        rank[e + u] = (unsigned char)((old >> sft) & 0xFFu);
                    }
                }
            }
        }
        __syncthreads();
        unsigned* gdst = (unsigned*)(ghist + (size_t)m * NN + base);  // 4B-aligned
        for (int i = threadIdx.x; i < nw; i += 256) gdst[i] = shw[i];
        return;
    }

    // ---- MFMA GEMM1 ----
    unsigned short* lb = (unsigned short*)sh;
    for (int i = threadIdx.x; i < 2048; i += 256)
        ((int4*)lb)[i] = ((const int4*)wbuf)[i];  // coalesced 32 KB stage
    __syncthreads();

    int wave = threadIdx.x >> 6;
    int lane = threadIdx.x & 63;
    int rowbase = blockIdx.x * 64 + wave * 16;
    int arow = rowbase + (lane & 15);
    int arowc = min(arow, NN - 1);
    int kgrp = (lane >> 4) * 8;

    f32x4 acc0 = {0.f, 0.f, 0.f, 0.f};
    f32x4 acc1 = {0.f, 0.f, 0.f, 0.f};
    const float* xrow = x + (size_t)arowc * FIN + kgrp;

    for (int sg = 0; sg < 16; sg += 4) {
        float4 av[8];
#pragma unroll
        for (int u = 0; u < 4; ++u) {
            av[2 * u]     = *(const float4*)(xrow + (sg + u) * 32);
            av[2 * u + 1] = *(const float4*)(xrow + (sg + u) * 32 + 4);
        }
#pragma unroll
        for (int u = 0; u < 4; ++u) {
            const float* s0 = (const float*)&av[2 * u];
            const float* s1 = (const float*)&av[2 * u + 1];
            union { bf16x8 v; unsigned w[4]; } af;
            af.w[0] = pk2bf(s0[0], s0[1]);
            af.w[1] = pk2bf(s0[2], s0[3]);
            af.w[2] = pk2bf(s1[0], s1[1]);
            af.w[3] = pk2bf(s1[2], s1[3]);
            int s = sg + u;
            bf16x8 b0 = *(const bf16x8*)(lb + ((size_t)(s * 2 + 0) * 64 + lane) * 8);
            bf16x8 b1 = *(const bf16x8*)(lb + ((size_t)(s * 2 + 1) * 64 + lane) * 8);
            acc0 = __builtin_amdgcn_mfma_f32_16x16x32_bf16(af.v, b0, acc0, 0, 0, 0);
            acc1 = __builtin_amdgcn_mfma_f32_16x16x32_bf16(af.v, b1, acc1, 0, 0, 0);
        }
    }

    int crow = rowbase + (lane >> 4) * 4;
    int ccol = lane & 15;
#pragma unroll
    for (int r = 0; r < 4; ++r) {
        if (crow + r < NN)
            h1p[(size_t)(crow + r) * 16 + ccol] = pk2bf(acc0[r], acc1[r]);
    }
}

// ---------------- SWAR slice-scan: 4 nodes/thread via u32 words ----------------

__global__ __launch_bounds__(256) void k_xscan(unsigned* __restrict__ ghistw,
                                               int* __restrict__ cnt,
                                               float* __restrict__ dis,
                                               int* __restrict__ part) {
    __shared__ int red[256];
    int widx = blockIdx.x * 256 + threadIdx.x;
    int tot = 0;
    if (widx < XW) {
        unsigned s0 = 0, s1 = 0, s2 = 0, s3 = 0;
        unsigned* p = ghistw + widx;
#pragma unroll 4
        for (int m = 0; m < M_SL; ++m) {
            unsigned w = p[(size_t)m * XW];
            p[(size_t)m * XW] = s0 | (s1 << 8) | (s2 << 16) | (s3 << 24);
            s0 += w & 0xFFu; s1 += (w >> 8) & 0xFFu;
            s2 += (w >> 16) & 0xFFu; s3 += (w >> 24) & 0xFFu;
        }
        int c0 = widx * 4;
        *(int4*)(cnt + c0) = make_int4(s0, s1, s2, s3);
        *(float4*)(dis + c0) = make_float4(rsqrtf((float)s0 + 1.f), rsqrtf((float)s1 + 1.f),
                                           rsqrtf((float)s2 + 1.f), rsqrtf((float)s3 + 1.f));
        tot = s0 + s1 + s2 + s3;
    }
    red[threadIdx.x] = tot;
    __syncthreads();
    for (int st = 128; st > 0; st >>= 1) {
        if (threadIdx.x < st) red[threadIdx.x] += red[threadIdx.x + st];
        __syncthreads();
    }
    if (threadIdx.x == 0) part[blockIdx.x] = red[0];
}

// ---------------- fused: off-scan (+ combined-base table)  +  h1s = bf16(h1p * dis) ----------------

__global__ __launch_bounds__(1024) void k_scan_off_scale(const int* __restrict__ cnt,
                                                         const int* __restrict__ part,
                                                         int* __restrict__ off,
                                                         const unsigned char* __restrict__ ghist,
                                                         int* __restrict__ cb,
                                                         const uint2* __restrict__ h1p2,
                                                         uint2* __restrict__ h1s2,
                                                         const float* __restrict__ dis) {
    int bid = blockIdx.x;
    if (bid < SOS_NB) {
        __shared__ int s[1024];
        __shared__ int sp[128];
        if (threadIdx.x < 128) sp[threadIdx.x] = (threadIdx.x < XSB) ? part[threadIdx.x] : 0;
        __syncthreads();
        for (int st = 1; st < 128; st <<= 1) {
            int a = (threadIdx.x < 128 && threadIdx.x >= st) ? sp[threadIdx.x - st] : 0;
            __syncthreads();
            if (threadIdx.x < 128) sp[threadIdx.x] += a;
            __syncthreads();
        }
        int pbase = (bid == 0) ? 0 : sp[bid - 1];
        int i = bid * 1024 + threadIdx.x;
        int v = (i < NN) ? cnt[i] : 0;
        s[threadIdx.x] = v;
        __syncthreads();
        for (int st = 1; st < 1024; st <<= 1) {
            int a = (threadIdx.x >= st) ? s[threadIdx.x - st] : 0;
            __syncthreads();
            s[threadIdx.x] += a;
            __syncthreads();
        }
        if (i < NN) {
            int o = pbase + s[threadIdx.x] - v;  // exclusive
            off[i] = o;
            // combined base: cb[m][i] = off[i] + per-slice prefix
#pragma unroll 4
            for (int m = 0; m < M_SL; ++m)
                cb[(size_t)m * NN + i] = o + (int)ghist[(size_t)m * NN + i];
        }
        if (i == NN - 1) off[NN] = pbase + s[threadIdx.x];
    } else {
        int idx = (bid - SOS_NB) * 1024 + threadIdx.x;  // uint2 index (4 bf16)
        if (idx < NN * 8) {
            uint2 v = h1p2[idx];
            float d = dis[idx >> 3];
            float a0 = bf2f((unsigned short)v.x), a1 = bf2f((unsigned short)(v.x >> 16));
            float a2 = bf2f((unsigned short)v.y), a3 = bf2f((unsigned short)(v.y >> 16));
            uint2 o;
            o.x = pk2bf(a0 * d, a1 * d);
            o.y = pk2bf(a2 * d, a3 * d);
            h1s2[idx] = o;
        }
    }
}

// ---------------- CSR fill: atomic-free, slot = cb[m][c] + rank, 8 edges/thread ----------------

__global__ void k_fill(const int* __restrict__ row, const int* __restrict__ col,
                       const unsigned char* __restrict__ rank,
                       const int* __restrict__ cb,
                       int* __restrict__ esrc) {
    int t = blockIdx.x * blockDim.x + threadIdx.x;
    if (t >= NE / 8) return;
#pragma unroll
    for (int qq = 0; qq < 2; ++qq) {
        int i = t * 2 + qq;  // quad index
        int m = i / QSL;     // slice
        int4 r4 = ((const int4*)row)[i];
        int4 c4 = ((const int4*)col)[i];
        uchar4 rk4 = ((const uchar4*)rank)[i];
        int rr[4] = {r4.x, r4.y, r4.z, r4.w};
        int cc[4] = {c4.x, c4.y, c4.z, c4.w};
        int rk[4] = {rk4.x, rk4.y, rk4.z, rk4.w};
        int b4[4];
#pragma unroll
        for (int u = 0; u < 4; ++u) b4[u] = cb[(size_t)m * NN + cc[u]];
#pragma unroll
        for (int u = 0; u < 4; ++u) esrc[b4[u] + rk[u]] = rr[u];
    }
}

// ---------------- gather1 (uint4 lanes) + relu + GEMM2: h2s = relu(...)@W2 * dis ----------------
// 64 nodes/block, 4 lanes/node; lane l owns words 4l..4l+3 = features (4l+j, 4l+16+j), j=0..3

__global__ __launch_bounds__(256) void k_gather1g2(const int* __restrict__ off,
                                                   const int* __restrict__ esrc,
                                                   const uint4* __restrict__ h1s4,
                                                   const float* __restrict__ dis,
                                                   const float* __restrict__ b1,
                                                   const float* __restrict__ W2,
                                                   float* __restrict__ h2s) {
    __shared__ float w2l[FH * FC];       // 2 KB
    __shared__ float hrl[64][FH + 4];    // stride 36: float4-aligned, conflict-free
    for (int i = threadIdx.x; i < FH * FC; i += 256) w2l[i] = W2[i];

    int ng = threadIdx.x >> 2;
    int l = threadIdx.x & 3;
    int g = blockIdx.x * 64 + ng;
    if (g < NN) {
        int s0 = off[g], s1 = off[g + 1];
        const uint4* hp = h1s4 + l;  // row stride 4 uint4
        float acc[4][8];
#pragma unroll
        for (int u = 0; u < 4; ++u)
#pragma unroll
            for (int k = 0; k < 8; ++k) acc[u][k] = 0.f;
        int i = s0;
        for (; i + 3 < s1; i += 4) {
            int r0 = esrc[i], r1 = esrc[i + 1], r2 = esrc[i + 2], r3 = esrc[i + 3];
            uint4 w0 = hp[(size_t)r0 * 4];
            uint4 w1 = hp[(size_t)r1 * 4];
            uint4 w2 = hp[(size_t)r2 * 4];
            uint4 w3 = hp[(size_t)r3 * 4];
            acc[0][0] += bf2f((unsigned short)w0.x); acc[0][1] += bf2f((unsigned short)(w0.x >> 16));
            acc[0][2] += bf2f((unsigned short)w0.y); acc[0][3] += bf2f((unsigned short)(w0.y >> 16));
            acc[0][4] += bf2f((unsigned short)w0.z); acc[0][5] += bf2f((unsigned short)(w0.z >> 16));
            acc[0][6] += bf2f((unsigned short)w0.w); acc[0][7] += bf2f((unsigned short)(w0.w >> 16));
            acc[1][0] += bf2f((unsigned short)w1.x); acc[1][1] += bf2f((unsigned short)(w1.x >> 16));
            acc[1][2] += bf2f((unsigned short)w1.y); acc[1][3] += bf2f((unsigned short)(w1.y >> 16));
            acc[1][4] += bf2f((unsigned short)w1.z); acc[1][5] += bf2f((unsigned short)(w1.z >> 16));
            acc[1][6] += bf2f((unsigned short)w1.w); acc[1][7] += bf2f((unsigned short)(w1.w >> 16));
            acc[2][0] += bf2f((unsigned short)w2.x); acc[2][1] += bf2f((unsigned short)(w2.x >> 16));
            acc[2][2] += bf2f((unsigned short)w2.y); acc[2][3] += bf2f((unsigned short)(w2.y >> 16));
            acc[2][4] += bf2f((unsigned short)w2.z); acc[2][5] += bf2f((unsigned short)(w2.z >> 16));
            acc[2][6] += bf2f((unsigned short)w2.w); acc[2][7] += bf2f((unsigned short)(w2.w >> 16));
            acc[3][0] += bf2f((unsigned short)w3.x); acc[3][1] += bf2f((unsigned short)(w3.x >> 16));
            acc[3][2] += bf2f((unsigned short)w3.y); acc[3][3] += bf2f((unsigned short)(w3.y >> 16));
            acc[3][4] += bf2f((unsigned short)w3.z); acc[3][5] += bf2f((unsigned short)(w3.z >> 16));
            acc[3][6] += bf2f((unsigned short)w3.w); acc[3][7] += bf2f((unsigned short)(w3.w >> 16));
        }
        for (; i < s1; ++i) {
            uint4 w = hp[(size_t)esrc[i] * 4];
            acc[0][0] += bf2f((unsigned short)w.x); acc[0][1] += bf2f((unsigned short)(w.x >> 16));
            acc[0][2] += bf2f((unsigned short)w.y); acc[0][3] += bf2f((unsigned short)(w.y >> 16));
            acc[0][4] += bf2f((unsigned short)w.z); acc[0][5] += bf2f((unsigned short)(w.z >> 16));
            acc[0][6] += bf2f((unsigned short)w.w); acc[0][7] += bf2f((unsigned short)(w.w >> 16));
        }
        uint4 ws = hp[(size_t)g * 4];
        acc[0][0] += bf2f((unsigned short)ws.x); acc[0][1] += bf2f((unsigned short)(ws.x >> 16));
        acc[0][2] += bf2f((unsigned short)ws.y); acc[0][3] += bf2f((unsigned short)(ws.y >> 16));
        acc[0][4] += bf2f((unsigned short)ws.z); acc[0][5] += bf2f((unsigned short)(ws.z >> 16));
        acc[0][6] += bf2f((unsigned short)ws.w); acc[0][7] += bf2f((unsigned short)(ws.w >> 16));
        float dg = dis[g];
        float4 blo = ((const float4*)b1)[l];       // b1[4l..4l+3]
        float4 bhi = ((const float4*)b1)[l + 4];   // b1[4l+16..4l+19]
        // feature f (lo): acc[*][2j] -> 4l+j ; (hi): acc[*][2j+1] -> 4l+16+j
        float f0 = acc[0][0] + acc[1][0] + acc[2][0] + acc[3][0];
        float f1 = acc[0][2] + acc[1][2] + acc[2][2] + acc[3][2];
        float f2 = acc[0][4] + acc[1][4] + acc[2][4] + acc[3][4];
        float f3 = acc[0][6] + acc[1][6] + acc[2][6] + acc[3][6];
        float h0 = acc[0][1] + acc[1][1] + acc[2][1] + acc[3][1];
        float h1 = acc[0][3] + acc[1][3] + acc[2][3] + acc[3][3];
        float h2 = acc[0][5] + acc[1][5] + acc[2][5] + acc[3][5];
        float h3 = acc[0][7] + acc[1][7] + acc[2][7] + acc[3][7];
        float v0 = dg * f0 + blo.x, v1 = dg * f1 + blo.y;
        float v2 = dg * f2 + blo.z, v3 = dg * f3 + blo.w;
        float u0 = dg * h0 + bhi.x, u1 = dg * h1 + bhi.y;
        float u2 = dg * h2 + bhi.z, u3 = dg * h3 + bhi.w;
        *(float4*)&hrl[ng][4 * l] = make_float4(v0 > 0.f ? v0 : 0.f, v1 > 0.f ? v1 : 0.f,
                                                v2 > 0.f ? v2 : 0.f, v3 > 0.f ? v3 : 0.f);
        *(float4*)&hrl[ng][4 * l + 16] = make_float4(u0 > 0.f ? u0 : 0.f, u1 > 0.f ? u1 : 0.f,
                                                     u2 > 0.f ? u2 : 0.f, u3 > 0.f ? u3 : 0.f);
    }
    __syncthreads();

    int j = threadIdx.x & 15;
#pragma unroll
    for (int q = 0; q < 4; ++q) {
        int n2 = (threadIdx.x >> 4) + q * 16;
        int g2 = blockIdx.x * 64 + n2;
        if (g2 < NN) {
            float s = 0.0f;
#pragma unroll
            for (int k = 0; k < FH; ++k) s += hrl[n2][k] * w2l[k * FC + j];
            h2s[(size_t)g2 * FC + j] = s * dis[g2];
        }
    }
}

// ---------------- gather2 (float4 lanes) + log_softmax -> out ----------------
// 64 nodes/block, 4 lanes/node, 4 classes/lane

__global__ __launch_bounds__(256) void k_gather2(const int* __restrict__ off,
                                                 const int* __restrict__ esrc,
                                                 const float* __restrict__ h2s,
                                                 const float* __restrict__ dis,
                                                 const float* __restrict__ b2,
                                                 float* __restrict__ out) {
    int ng = threadIdx.x >> 2;
    int l = threadIdx.x & 3;
    int g = blockIdx.x * 64 + ng;
    if (g >= NN) return;
    int s0 = off[g], s1 = off[g + 1];
    const float4* hp = (const float4*)h2s + l;  // row stride 4 float4
    float ax0 = 0.f, ay0 = 0.f, az0 = 0.f, aw0 = 0.f;
    float ax1 = 0.f, ay1 = 0.f, az1 = 0.f, aw1 = 0.f;
    float ax2 = 0.f, ay2 = 0.f, az2 = 0.f, aw2 = 0.f;
    float ax3 = 0.f, ay3 = 0.f, az3 = 0.f, aw3 = 0.f;
    int i = s0;
    for (; i + 3 < s1; i += 4) {
        int r0 = esrc[i], r1 = esrc[i + 1], r2 = esrc[i + 2], r3 = esrc[i + 3];
        float4 t0 = hp[(size_t)r0 * 4];
        float4 t1 = hp[(size_t)r1 * 4];
        float4 t2 = hp[(size_t)r2 * 4];
        float4 t3 = hp[(size_t)r3 * 4];
        ax0 += t0.x; ay0 += t0.y; az0 += t0.z; aw0 += t0.w;
        ax1 += t1.x; ay1 += t1.y; az1 += t1.z; aw1 += t1.w;
        ax2 += t2.x; ay2 += t2.y; az2 += t2.z; aw2 += t2.w;
        ax3 += t3.x; ay3 += t3.y; az3 += t3.z; aw3 += t3.w;
    }
    for (; i < s1; ++i) {
        float4 t = hp[(size_t)esrc[i] * 4];
        ax0 += t.x; ay0 += t.y; az0 += t.z; aw0 += t.w;
    }
    float4 ts = hp[(size_t)g * 4];
    float vx = ax0 + ax1 + ax2 + ax3 + ts.x;
    float vy = ay0 + ay1 + ay2 + ay3 + ts.y;
    float vz = az0 + az1 + az2 + az3 + ts.z;
    float vw = aw0 + aw1 + aw2 + aw3 + ts.w;
    float dg = dis[g];
    float4 bb = ((const float4*)b2)[l];
    vx = dg * vx + bb.x;
    vy = dg * vy + bb.y;
    vz = dg * vz + bb.z;
    vw = dg * vw + bb.w;
    float m = fmaxf(fmaxf(vx, vy), fmaxf(vz, vw));
#pragma unroll
    for (int o = 1; o < 4; o <<= 1) m = fmaxf(m, __shfl_xor(m, o, 4));
    float e = __expf(vx - m) + __expf(vy - m) + __expf(vz - m) + __expf(vw - m);
    float s = e;
#pragma unroll
    for (int o = 1; o < 4; o <<= 1) s += __shfl_xor(s, o, 4);
    float ls = m + logf(s);
    ((float4*)out)[(size_t)g * 4 + l] = make_float4(vx - ls, vy - ls, vz - ls, vw - ls);
}

extern "C" void kernel_launch(void* const* d_in, const int* in_sizes, int n_in,
                              void* d_out, int out_size, void* d_ws, size_t ws_size,
                              hipStream_t stream) {
    const float* x  = (const float*)d_in[0];
    const int*   ei = (const int*)d_in[1];
    const float* W1 = (const float*)d_in[2];
    const float* b1 = (const float*)d_in[3];
    const float* W2 = (const float*)d_in[4];
    const float* b2 = (const float*)d_in[5];
    float* out = (float*)d_out;

    const int* row = ei;
    const int* col = ei + NE;

    // workspace layout (int units, ~39 MB; all regions 16B-aligned)
    int* base = (int*)d_ws;
    unsigned char* ghist = (unsigned char*)base;            // M_SL*NN u8 = 800K ints
    unsigned char* rank  = ghist + (size_t)M_SL * NN;       // NE u8 = 400K ints
    int*   cnt   = base + 800000 + 400000;                  // NN
    int*   off   = cnt + NN;                                // NN+1 (pad 8)
    int*   part  = off + NN + 8;                            // 128
    float* dis   = (float*)(part + 128);                    // NN
    unsigned short* wbuf = (unsigned short*)(dis + NN);     // 16384 u16 = 8192 ints
    unsigned* h1p = (unsigned*)(wbuf + 16384);              // NN*16 u32 (1.6M ints)
    unsigned* h1s = h1p + (size_t)NN * 16;                  // NN*16 u32 (1.6M ints)
    int*   esrc  = (int*)(h1s + (size_t)NN * 16);           // NE (1.6M ints)
    int*   cb    = esrc + NE;                               // M_SL*NN ints (3.2M)
    float* h2s   = (float*)h1p;                             // alias: h1p dead after scale

    const int B = 256;

    k_prep<<<1, B, 0, stream>>>(W1, wbuf);
    k_hist_gemm1<<<NGB1 + NHB, B, 0, stream>>>(col, ghist, rank, x, wbuf, h1p);
    k_xscan<<<XSB, B, 0, stream>>>((unsigned*)ghist, cnt, dis, part);
    k_scan_off_scale<<<SOS_NB + SCALE_B, 1024, 0, stream>>>(cnt, part, off, ghist, cb,
                                                            (const uint2*)h1p, (uint2*)h1s, dis);
    k_fill<<<NCB2, B, 0, stream>>>(row, col, rank, cb, esrc);
    k_gather1g2<<<(NN + 63) / 64, B, 0, stream>>>(off, esrc, (const uint4*)h1s, dis, b1, W2, h2s);
    k_gather2<<<(NN + 63) / 64, B, 0, stream>>>(off, esrc, h2s, dis, b2, out);
}

// Round 17
// 171.298 us; speedup vs baseline: 1.0739x; 1.0739x over previous
//
#include <hip/hip_runtime.h>
#include <hip/hip_bf16.h>

#define NN 100000
#define NE 1600000
#define FIN 512
#define FH 32
#define FC 16
#define NCB2 ((NE / 8 + 255) / 256)         // 782 fill blocks (8 edges/thread)
#define M_SL 32                             // edge slices
#define SLICE (NE / M_SL)                   // 50000 edges/slice
#define QSL (SLICE / 4)                     // 12500 quads/slice
#define PSZ 32768                           // nodes per pass (byte-packed 32 KB LDS)
#define NP ((NN + PSZ - 1) / PSZ)           // 4 passes
#define NHB (M_SL * NP)                     // 128 hist blocks
#define NGB1 ((NN + 63) / 64)               // 1563 MFMA gemm blocks
#define XW (NN / 4)                         // 25000 ghist words per slice
#define XSB ((XW + 255) / 256)              // 98 xscan blocks
#define SOS_NB 98                           // off-scan blocks (1024 nodes each)
#define SCB (NN * 8 / 256)                  // 3125 scale blocks (256 uint2/block)

typedef __attribute__((ext_vector_type(8))) short bf16x8;
typedef __attribute__((ext_vector_type(4))) float f32x4;

__device__ inline unsigned short f2bf(float f) {
    unsigned u = __float_as_uint(f);
    return (unsigned short)((u + 0x7FFFu + ((u >> 16) & 1u)) >> 16);  // RNE
}
__device__ inline float bf2f(unsigned short u) {
    return __uint_as_float(((unsigned)u) << 16);
}
__device__ inline unsigned pk2bf(float a, float b) {  // packed 2xbf16 via v_cvt_pk_bf16_f32
    __hip_bfloat162 p = __float22bfloat162_rn(make_float2(a, b));
    union { __hip_bfloat162 h; unsigned u; } c;
    c.h = p;
    return c.u;
}

// ---------------- prep: W1 -> bf16, pre-swizzled to B-fragment order ----------------

__global__ __launch_bounds__(256) void k_prep(const float* __restrict__ W1,
                                              unsigned short* __restrict__ wbuf) {
    for (int idx = threadIdx.x; idx < 16 * 2 * 64; idx += 256) {
        int s = idx >> 7;
        int t = (idx >> 6) & 1;
        int l = idx & 63;
        int k0 = s * 32 + (l >> 4) * 8;
        int c = t * 16 + (l & 15);
        bf16x8 w;
#pragma unroll
        for (int i = 0; i < 8; ++i) w[i] = (short)f2bf(W1[(size_t)(k0 + i) * FH + c]);
        *(bf16x8*)(wbuf + (size_t)idx * 8) = w;
    }
}

// ---------------- fused: MFMA GEMM1 (bf16 permuted out)  +  byte-packed LDS hist ----------------
// h1p layout: row = 16 u32 words; word w packs (col w, col w+16) as 2xbf16.

__global__ __launch_bounds__(256) void k_hist_gemm1(const int* __restrict__ col,
                                                    unsigned char* __restrict__ ghist,
                                                    unsigned char* __restrict__ rank,
                                                    const float* __restrict__ x,
                                                    const unsigned short* __restrict__ wbuf,
                                                    unsigned* __restrict__ h1p) {
    __shared__ int sh[PSZ / 4];  // 32 KB; gemm path reuses as bf16 W store

    if (blockIdx.x >= NGB1) {
        int hb = blockIdx.x - NGB1;
        int p = hb / M_SL;
        int m = hb % M_SL;
        int base = p * PSZ;
        int nb = min(PSZ, NN - base);
        int nw = (nb + 3) >> 2;
        unsigned* shw = (unsigned*)sh;
        for (int i = threadIdx.x; i < nw; i += 256) shw[i] = 0u;
        __syncthreads();
        const int4* c4p = (const int4*)(col + m * SLICE);
        for (int it = 0; it < (QSL + 255) / 256; ++it) {
            int q = it * 256 + threadIdx.x;
            if (q < QSL) {
                int4 c4 = c4p[q];
                int e = m * SLICE + q * 4;
                int cc[4] = {c4.x, c4.y, c4.z, c4.w};
#pragma unroll
                for (int u = 0; u < 4; ++u) {
                    int d = cc[u] - base;
                    if ((unsigned)d < (unsigned)nb) {
                        int sft = 8 * (d & 3);
                        unsigned old = atomicAdd(&shw[d >> 2], 1u << sft);
                        rank[e + u] = (unsigned char)((old >> sft) & 0xFFu);
                    }
                }
            }
        }
        __syncthreads();
        unsigned* gdst = (unsigned*)(ghist + (size_t)m * NN + base);  // 4B-aligned
        for (int i = threadIdx.x; i < nw; i += 256) gdst[i] = shw[i];
        return;
    }

    // ---- MFMA GEMM1 ----
    unsigned short* lb = (unsigned short*)sh;
    for (int i = threadIdx.x; i < 2048; i += 256)
        ((int4*)lb)[i] = ((const int4*)wbuf)[i];  // coalesced 32 KB stage
    __syncthreads();

    int wave = threadIdx.x >> 6;
    int lane = threadIdx.x & 63;
    int rowbase = blockIdx.x * 64 + wave * 16;
    int arow = rowbase + (lane & 15);
    int arowc = min(arow, NN - 1);
    int kgrp = (lane >> 4) * 8;

    f32x4 acc0 = {0.f, 0.f, 0.f, 0.f};
    f32x4 acc1 = {0.f, 0.f, 0.f, 0.f};
    const float* xrow = x + (size_t)arowc * FIN + kgrp;

    for (int sg = 0; sg < 16; sg += 4) {
        float4 av[8];
#pragma unroll
        for (int u = 0; u < 4; ++u) {
            av[2 * u]     = *(const float4*)(xrow + (sg + u) * 32);
            av[2 * u + 1] = *(const float4*)(xrow + (sg + u) * 32 + 4);
        }
#pragma unroll
        for (int u = 0; u < 4; ++u) {
            const float* s0 = (const float*)&av[2 * u];
            const float* s1 = (const float*)&av[2 * u + 1];
            union { bf16x8 v; unsigned w[4]; } af;
            af.w[0] = pk2bf(s0[0], s0[1]);
            af.w[1] = pk2bf(s0[2], s0[3]);
            af.w[2] = pk2bf(s1[0], s1[1]);
            af.w[3] = pk2bf(s1[2], s1[3]);
            int s = sg + u;
            bf16x8 b0 = *(const bf16x8*)(lb + ((size_t)(s * 2 + 0) * 64 + lane) * 8);
            bf16x8 b1 = *(const bf16x8*)(lb + ((size_t)(s * 2 + 1) * 64 + lane) * 8);
            acc0 = __builtin_amdgcn_mfma_f32_16x16x32_bf16(af.v, b0, acc0, 0, 0, 0);
            acc1 = __builtin_amdgcn_mfma_f32_16x16x32_bf16(af.v, b1, acc1, 0, 0, 0);
        }
    }

    int crow = rowbase + (lane >> 4) * 4;
    int ccol = lane & 15;
#pragma unroll
    for (int r = 0; r < 4; ++r) {
        if (crow + r < NN)
            h1p[(size_t)(crow + r) * 16 + ccol] = pk2bf(acc0[r], acc1[r]);
    }
}

// ---------------- SWAR slice-scan: 4 nodes/thread via u32 words ----------------

__global__ __launch_bounds__(256) void k_xscan(unsigned* __restrict__ ghistw,
                                               int* __restrict__ cnt,
                                               float* __restrict__ dis,
                                               int* __restrict__ part) {
    __shared__ int red[256];
    int widx = blockIdx.x * 256 + threadIdx.x;
    int tot = 0;
    if (widx < XW) {
        unsigned s0 = 0, s1 = 0, s2 = 0, s3 = 0;
        unsigned* p = ghistw + widx;
#pragma unroll 4
        for (int m = 0; m < M_SL; ++m) {
            unsigned w = p[(size_t)m * XW];
            p[(size_t)m * XW] = s0 | (s1 << 8) | (s2 << 16) | (s3 << 24);
            s0 += w & 0xFFu; s1 += (w >> 8) & 0xFFu;
            s2 += (w >> 16) & 0xFFu; s3 += (w >> 24) & 0xFFu;
        }
        int c0 = widx * 4;
        *(int4*)(cnt + c0) = make_int4(s0, s1, s2, s3);
        *(float4*)(dis + c0) = make_float4(rsqrtf((float)s0 + 1.f), rsqrtf((float)s1 + 1.f),
                                           rsqrtf((float)s2 + 1.f), rsqrtf((float)s3 + 1.f));
        tot = s0 + s1 + s2 + s3;
    }
    red[threadIdx.x] = tot;
    __syncthreads();
    for (int st = 128; st > 0; st >>= 1) {
        if (threadIdx.x < st) red[threadIdx.x] += red[threadIdx.x + st];
        __syncthreads();
    }
    if (threadIdx.x == 0) part[blockIdx.x] = red[0];
}

// ---------------- off-scan (inline part-scan) ----------------

__global__ __launch_bounds__(1024) void k_scan_off(const int* __restrict__ cnt,
                                                   const int* __restrict__ part,
                                                   int* __restrict__ off) {
    __shared__ int s[1024];
    __shared__ int sp[128];
    int bid = blockIdx.x;
    if (threadIdx.x < 128) sp[threadIdx.x] = (threadIdx.x < XSB) ? part[threadIdx.x] : 0;
    __syncthreads();
    for (int st = 1; st < 128; st <<= 1) {
        int a = (threadIdx.x < 128 && threadIdx.x >= st) ? sp[threadIdx.x - st] : 0;
        __syncthreads();
        if (threadIdx.x < 128) sp[threadIdx.x] += a;
        __syncthreads();
    }
    int pbase = (bid == 0) ? 0 : sp[bid - 1];
    int i = bid * 1024 + threadIdx.x;
    int v = (i < NN) ? cnt[i] : 0;
    s[threadIdx.x] = v;
    __syncthreads();
    for (int st = 1; st < 1024; st <<= 1) {
        int a = (threadIdx.x >= st) ? s[threadIdx.x - st] : 0;
        __syncthreads();
        s[threadIdx.x] += a;
        __syncthreads();
    }
    if (i < NN) off[i] = pbase + s[threadIdx.x] - v;  // exclusive
    if (i == NN - 1) off[NN] = pbase + s[threadIdx.x];
}

// ---------------- fused: CSR fill (8 edges/thread)  +  h1s = bf16(h1p * dis) ----------------
// blocks [0, NCB2): fill; blocks [NCB2, NCB2+SCB): scale (independent work, overlapped)

__global__ __launch_bounds__(256) void k_fill_scale(const int* __restrict__ row,
                                                    const int* __restrict__ col,
                                                    const unsigned char* __restrict__ rank,
                                                    const int* __restrict__ off,
                                                    const unsigned char* __restrict__ ghist,
                                                    int* __restrict__ esrc,
                                                    const uint2* __restrict__ h1p2,
                                                    uint2* __restrict__ h1s2,
                                                    const float* __restrict__ dis) {
    if (blockIdx.x >= NCB2) {
        int idx = (blockIdx.x - NCB2) * 256 + threadIdx.x;  // uint2 index (4 bf16)
        uint2 v = h1p2[idx];
        float d = dis[idx >> 3];
        float a0 = bf2f((unsigned short)v.x), a1 = bf2f((unsigned short)(v.x >> 16));
        float a2 = bf2f((unsigned short)v.y), a3 = bf2f((unsigned short)(v.y >> 16));
        uint2 o;
        o.x = pk2bf(a0 * d, a1 * d);
        o.y = pk2bf(a2 * d, a3 * d);
        h1s2[idx] = o;
        return;
    }
    int t = blockIdx.x * blockDim.x + threadIdx.x;
    if (t >= NE / 8) return;
#pragma unroll
    for (int qq = 0; qq < 2; ++qq) {
        int i = t * 2 + qq;  // quad index
        int m = i / QSL;     // slice
        int4 r4 = ((const int4*)row)[i];
        int4 c4 = ((const int4*)col)[i];
        uchar4 rk4 = ((const uchar4*)rank)[i];
        int rr[4] = {r4.x, r4.y, r4.z, r4.w};
        int cc[4] = {c4.x, c4.y, c4.z, c4.w};
        int rk[4] = {rk4.x, rk4.y, rk4.z, rk4.w};
        int o4[4], bp[4];
#pragma unroll
        for (int u = 0; u < 4; ++u) o4[u] = off[cc[u]];
#pragma unroll
        for (int u = 0; u < 4; ++u) bp[u] = ghist[(size_t)m * NN + cc[u]];
#pragma unroll
        for (int u = 0; u < 4; ++u) esrc[o4[u] + bp[u] + rk[u]] = rr[u];
    }
}

// ---------------- gather1 (uint2 lanes) + relu + GEMM2: h2s = relu(...)@W2 * dis ----------------
// 32 nodes/block, 8 lanes/node; lane l owns words {2l, 2l+1} = features (2l, 2l+16, 2l+1, 2l+17)

__global__ __launch_bounds__(256) void k_gather1g2(const int* __restrict__ off,
                                                   const int* __restrict__ esrc,
                                                   const unsigned* __restrict__ h1s,
                                                   const float* __restrict__ dis,
                                                   const float* __restrict__ b1,
                                                   const float* __restrict__ W2,
                                                   float* __restrict__ h2s) {
    __shared__ float w2l[FH * FC];       // 2 KB
    __shared__ float hrl[32][FH + 2];    // stride 34 (even): conflict-free, float2-aligned
    for (int i = threadIdx.x; i < FH * FC; i += 256) w2l[i] = W2[i];

    int ng = threadIdx.x >> 3;
    int l = threadIdx.x & 7;
    int g = blockIdx.x * 32 + ng;
    int s0 = off[g], s1 = off[g + 1];
    const uint2* hp = (const uint2*)h1s + l;  // row stride 8 uint2
    float a00 = 0.f, a01 = 0.f, a02 = 0.f, a03 = 0.f;
    float a10 = 0.f, a11 = 0.f, a12 = 0.f, a13 = 0.f;
    float a20 = 0.f, a21 = 0.f, a22 = 0.f, a23 = 0.f;
    float a30 = 0.f, a31 = 0.f, a32 = 0.f, a33 = 0.f;
    int i = s0;
    for (; i + 3 < s1; i += 4) {
        int r0 = esrc[i], r1 = esrc[i + 1], r2 = esrc[i + 2], r3 = esrc[i + 3];
        uint2 w0 = hp[(size_t)r0 * 8];
        uint2 w1 = hp[(size_t)r1 * 8];
        uint2 w2 = hp[(size_t)r2 * 8];
        uint2 w3 = hp[(size_t)r3 * 8];
        a00 += bf2f((unsigned short)w0.x); a01 += bf2f((unsigned short)(w0.x >> 16));
        a02 += bf2f((unsigned short)w0.y); a03 += bf2f((unsigned short)(w0.y >> 16));
        a10 += bf2f((unsigned short)w1.x); a11 += bf2f((unsigned short)(w1.x >> 16));
        a12 += bf2f((unsigned short)w1.y); a13 += bf2f((unsigned short)(w1.y >> 16));
        a20 += bf2f((unsigned short)w2.x); a21 += bf2f((unsigned short)(w2.x >> 16));
        a22 += bf2f((unsigned short)w2.y); a23 += bf2f((unsigned short)(w2.y >> 16));
        a30 += bf2f((unsigned short)w3.x); a31 += bf2f((unsigned short)(w3.x >> 16));
        a32 += bf2f((unsigned short)w3.y); a33 += bf2f((unsigned short)(w3.y >> 16));
    }
    for (; i < s1; ++i) {
        uint2 w = hp[(size_t)esrc[i] * 8];
        a00 += bf2f((unsigned short)w.x); a01 += bf2f((unsigned short)(w.x >> 16));
        a02 += bf2f((unsigned short)w.y); a03 += bf2f((unsigned short)(w.y >> 16));
    }
    uint2 ws = hp[(size_t)g * 8];
    float f0 = a00 + a10 + a20 + a30 + bf2f((unsigned short)ws.x);   // feature 2l
    float f16 = a01 + a11 + a21 + a31 + bf2f((unsigned short)(ws.x >> 16));  // 2l+16
    float f1 = a02 + a12 + a22 + a32 + bf2f((unsigned short)ws.y);   // 2l+1
    float f17 = a03 + a13 + a23 + a33 + bf2f((unsigned short)(ws.y >> 16)); // 2l+17
    float dg = dis[g];
    float2 blo = ((const float2*)b1)[l];       // b1[2l], b1[2l+1]
    float2 bhi = ((const float2*)b1)[l + 8];   // b1[2l+16], b1[2l+17]
    float v0 = dg * f0 + blo.x;
    float v1 = dg * f1 + blo.y;
    float v16 = dg * f16 + bhi.x;
    float v17 = dg * f17 + bhi.y;
    *(float2*)&hrl[ng][2 * l] = make_float2(v0 > 0.f ? v0 : 0.f, v1 > 0.f ? v1 : 0.f);
    *(float2*)&hrl[ng][2 * l + 16] = make_float2(v16 > 0.f ? v16 : 0.f, v17 > 0.f ? v17 : 0.f);
    __syncthreads();

    int j = threadIdx.x & 15;
#pragma unroll
    for (int half = 0; half < 2; ++half) {
        int n2 = (threadIdx.x >> 4) + half * 16;
        int g2 = blockIdx.x * 32 + n2;
        float s = 0.0f;
#pragma unroll
        for (int k = 0; k < FH; ++k) s += hrl[n2][k] * w2l[k * FC + j];
        h2s[(size_t)g2 * FC + j] = s * dis[g2];
    }
}

// ---------------- gather2 (float4 lanes) + log_softmax -> out ----------------
// 64 nodes/block, 4 lanes/node, 4 classes/lane

__global__ __launch_bounds__(256) void k_gather2(const int* __restrict__ off,
                                                 const int* __restrict__ esrc,
                                                 const float* __restrict__ h2s,
                                                 const float* __restrict__ dis,
                                                 const float* __restrict__ b2,
                                                 float* __restrict__ out) {
    int ng = threadIdx.x >> 2;
    int l = threadIdx.x & 3;
    int g = blockIdx.x * 64 + ng;
    if (g >= NN) return;
    int s0 = off[g], s1 = off[g + 1];
    const float4* hp = (const float4*)h2s + l;  // row stride 4 float4
    float ax0 = 0.f, ay0 = 0.f, az0 = 0.f, aw0 = 0.f;
    float ax1 = 0.f, ay1 = 0.f, az1 = 0.f, aw1 = 0.f;
    float ax2 = 0.f, ay2 = 0.f, az2 = 0.f, aw2 = 0.f;
    float ax3 = 0.f, ay3 = 0.f, az3 = 0.f, aw3 = 0.f;
    int i = s0;
    for (; i + 3 < s1; i += 4) {
        int r0 = esrc[i], r1 = esrc[i + 1], r2 = esrc[i + 2], r3 = esrc[i + 3];
        float4 t0 = hp[(size_t)r0 * 4];
        float4 t1 = hp[(size_t)r1 * 4];
        float4 t2 = hp[(size_t)r2 * 4];
        float4 t3 = hp[(size_t)r3 * 4];
        ax0 += t0.x; ay0 += t0.y; az0 += t0.z; aw0 += t0.w;
        ax1 += t1.x; ay1 += t1.y; az1 += t1.z; aw1 += t1.w;
        ax2 += t2.x; ay2 += t2.y; az2 += t2.z; aw2 += t2.w;
        ax3 += t3.x; ay3 += t3.y; az3 += t3.z; aw3 += t3.w;
    }
    for (; i < s1; ++i) {
        float4 t = hp[(size_t)esrc[i] * 4];
        ax0 += t.x; ay0 += t.y; az0 += t.z; aw0 += t.w;
    }
    float4 ts = hp[(size_t)g * 4];
    float vx = ax0 + ax1 + ax2 + ax3 + ts.x;
    float vy = ay0 + ay1 + ay2 + ay3 + ts.y;
    float vz = az0 + az1 + az2 + az3 + ts.z;
    float vw = aw0 + aw1 + aw2 + aw3 + ts.w;
    float dg = dis[g];
    float4 bb = ((const float4*)b2)[l];
    vx = dg * vx + bb.x;
    vy = dg * vy + bb.y;
    vz = dg * vz + bb.z;
    vw = dg * vw + bb.w;
    float m = fmaxf(fmaxf(vx, vy), fmaxf(vz, vw));
#pragma unroll
    for (int o = 1; o < 4; o <<= 1) m = fmaxf(m, __shfl_xor(m, o, 4));
    float e = __expf(vx - m) + __expf(vy - m) + __expf(vz - m) + __expf(vw - m);
    float s = e;
#pragma unroll
    for (int o = 1; o < 4; o <<= 1) s += __shfl_xor(s, o, 4);
    float ls = m + logf(s);
    ((float4*)out)[(size_t)g * 4 + l] = make_float4(vx - ls, vy - ls, vz - ls, vw - ls);
}

extern "C" void kernel_launch(void* const* d_in, const int* in_sizes, int n_in,
                              void* d_out, int out_size, void* d_ws, size_t ws_size,
                              hipStream_t stream) {
    const float* x  = (const float*)d_in[0];
    const int*   ei = (const int*)d_in[1];
    const float* W1 = (const float*)d_in[2];
    const float* b1 = (const float*)d_in[3];
    const float* W2 = (const float*)d_in[4];
    const float* b2 = (const float*)d_in[5];
    float* out = (float*)d_out;

    const int* row = ei;
    const int* col = ei + NE;

    // workspace layout (int units, ~26 MB; all regions 16B-aligned)
    int* base = (int*)d_ws;
    unsigned char* ghist = (unsigned char*)base;            // M_SL*NN u8 = 800K ints
    unsigned char* rank  = ghist + (size_t)M_SL * NN;       // NE u8 = 400K ints
    int*   cnt   = base + 800000 + 400000;                  // NN
    int*   off   = cnt + NN;                                // NN+1 (pad 8)
    int*   part  = off + NN + 8;                            // 128
    float* dis   = (float*)(part + 128);                    // NN
    unsigned short* wbuf = (unsigned short*)(dis + NN);     // 16384 u16 = 8192 ints
    unsigned* h1p = (unsigned*)(wbuf + 16384);              // NN*16 u32 (1.6M ints)
    unsigned* h1s = h1p + (size_t)NN * 16;                  // NN*16 u32 (1.6M ints)
    int*   esrc  = (int*)(h1s + (size_t)NN * 16);           // NE (1.6M ints)
    float* h2s   = (float*)h1p;                             // alias: h1p dead after scale

    const int B = 256;

    k_prep<<<1, B, 0, stream>>>(W1, wbuf);
    k_hist_gemm1<<<NGB1 + NHB, B, 0, stream>>>(col, ghist, rank, x, wbuf, h1p);
    k_xscan<<<XSB, B, 0, stream>>>((unsigned*)ghist, cnt, dis, part);
    k_scan_off<<<SOS_NB, 1024, 0, stream>>>(cnt, part, off);
    k_fill_scale<<<NCB2 + SCB, B, 0, stream>>>(row, col, rank, off, ghist, esrc,
                                               (const uint2*)h1p, (uint2*)h1s, dis);
    k_gather1g2<<<NN / 32, B, 0, stream>>>(off, esrc, h1s, dis, b1, W2, h2s);
    k_gather2<<<(NN + 63) / 64, B, 0, stream>>>(off, esrc, h2s, dis, b2, out);
}

// Round 18
// 170.777 us; speedup vs baseline: 1.0772x; 1.0031x over previous
//
#include <hip/hip_runtime.h>
#include <hip/hip_bf16.h>

#define NN 100000
#define NE 1600000
#define FIN 512
#define FH 32
#define FC 16
#define NCB2 ((NE / 8 + 255) / 256)         // 782 fill blocks (8 edges/thread)
#define M_SL 32                             // edge slices
#define SLICE (NE / M_SL)                   // 50000 edges/slice
#define QSL (SLICE / 4)                     // 12500 quads/slice
#define PSZ 32768                           // nodes per pass (byte-packed 32 KB LDS)
#define NP ((NN + PSZ - 1) / PSZ)           // 4 passes
#define NHB (M_SL * NP)                     // 128 hist blocks
#define NGB1 ((NN + 63) / 64)               // 1563 MFMA gemm blocks
#define XW (NN / 4)                         // 25000 ghist words per slice
#define XSB ((XW + 255) / 256)              // 98 xscan blocks
#define SOS_NB 98                           // off-scan blocks (1024 nodes each)

typedef __attribute__((ext_vector_type(8))) short bf16x8;
typedef __attribute__((ext_vector_type(4))) float f32x4;

__device__ inline unsigned short f2bf(float f) {
    unsigned u = __float_as_uint(f);
    return (unsigned short)((u + 0x7FFFu + ((u >> 16) & 1u)) >> 16);  // RNE
}
__device__ inline float bf2f(unsigned short u) {
    return __uint_as_float(((unsigned)u) << 16);
}
__device__ inline unsigned pk2bf(float a, float b) {  // packed 2xbf16 via v_cvt_pk_bf16_f32
    __hip_bfloat162 p = __float22bfloat162_rn(make_float2(a, b));
    union { __hip_bfloat162 h; unsigned u; } c;
    c.h = p;
    return c.u;
}

// ---------------- prep: W1 -> bf16, pre-swizzled to B-fragment order ----------------

__global__ __launch_bounds__(256) void k_prep(const float* __restrict__ W1,
                                              unsigned short* __restrict__ wbuf) {
    for (int idx = threadIdx.x; idx < 16 * 2 * 64; idx += 256) {
        int s = idx >> 7;
        int t = (idx >> 6) & 1;
        int l = idx & 63;
        int k0 = s * 32 + (l >> 4) * 8;
        int c = t * 16 + (l & 15);
        bf16x8 w;
#pragma unroll
        for (int i = 0; i < 8; ++i) w[i] = (short)f2bf(W1[(size_t)(k0 + i) * FH + c]);
        *(bf16x8*)(wbuf + (size_t)idx * 8) = w;
    }
}

// ---------------- fused: MFMA GEMM1 (bf16 permuted out)  +  byte-packed LDS hist ----------------
// h1p layout: row = 16 u32 words; word w packs (col w, col w+16) as 2xbf16.

__global__ __launch_bounds__(256) void k_hist_gemm1(const int* __restrict__ col,
                                                    unsigned char* __restrict__ ghist,
                                                    unsigned char* __restrict__ rank,
                                                    const float* __restrict__ x,
                                                    const unsigned short* __restrict__ wbuf,
                                                    unsigned* __restrict__ h1p) {
    __shared__ int sh[PSZ / 4];  // 32 KB; gemm path reuses as bf16 W store

    if (blockIdx.x >= NGB1) {
        int hb = blockIdx.x - NGB1;
        int p = hb / M_SL;
        int m = hb % M_SL;
        int base = p * PSZ;
        int nb = min(PSZ, NN - base);
        int nw = (nb + 3) >> 2;
        unsigned* shw = (unsigned*)sh;
        for (int i = threadIdx.x; i < nw; i += 256) shw[i] = 0u;
        __syncthreads();
        const int4* c4p = (const int4*)(col + m * SLICE);
        for (int it = 0; it < (QSL + 255) / 256; ++it) {
            int q = it * 256 + threadIdx.x;
            if (q < QSL) {
                int4 c4 = c4p[q];
                int e = m * SLICE + q * 4;
                int cc[4] = {c4.x, c4.y, c4.z, c4.w};
#pragma unroll
                for (int u = 0; u < 4; ++u) {
                    int d = cc[u] - base;
                    if ((unsigned)d < (unsigned)nb) {
                        int sft = 8 * (d & 3);
                        unsigned old = atomicAdd(&shw[d >> 2], 1u << sft);
                        rank[e + u] = (unsigned char)((old >> sft) & 0xFFu);
                    }
                }
            }
        }
        __syncthreads();
        unsigned* gdst = (unsigned*)(ghist + (size_t)m * NN + base);  // 4B-aligned
        for (int i = threadIdx.x; i < nw; i += 256) gdst[i] = shw[i];
        return;
    }

    // ---- MFMA GEMM1 ----
    unsigned short* lb = (unsigned short*)sh;
    for (int i = threadIdx.x; i < 2048; i += 256)
        ((int4*)lb)[i] = ((const int4*)wbuf)[i];  // coalesced 32 KB stage
    __syncthreads();

    int wave = threadIdx.x >> 6;
    int lane = threadIdx.x & 63;
    int rowbase = blockIdx.x * 64 + wave * 16;
    int arow = rowbase + (lane & 15);
    int arowc = min(arow, NN - 1);
    int kgrp = (lane >> 4) * 8;

    f32x4 acc0 = {0.f, 0.f, 0.f, 0.f};
    f32x4 acc1 = {0.f, 0.f, 0.f, 0.f};
    const float* xrow = x + (size_t)arowc * FIN + kgrp;

    for (int sg = 0; sg < 16; sg += 4) {
        float4 av[8];
#pragma unroll
        for (int u = 0; u < 4; ++u) {
            av[2 * u]     = *(const float4*)(xrow + (sg + u) * 32);
            av[2 * u + 1] = *(const float4*)(xrow + (sg + u) * 32 + 4);
        }
#pragma unroll
        for (int u = 0; u < 4; ++u) {
            const float* s0 = (const float*)&av[2 * u];
            const float* s1 = (const float*)&av[2 * u + 1];
            union { bf16x8 v; unsigned w[4]; } af;
            af.w[0] = pk2bf(s0[0], s0[1]);
            af.w[1] = pk2bf(s0[2], s0[3]);
            af.w[2] = pk2bf(s1[0], s1[1]);
            af.w[3] = pk2bf(s1[2], s1[3]);
            int s = sg + u;
            bf16x8 b0 = *(const bf16x8*)(lb + ((size_t)(s * 2 + 0) * 64 + lane) * 8);
            bf16x8 b1 = *(const bf16x8*)(lb + ((size_t)(s * 2 + 1) * 64 + lane) * 8);
            acc0 = __builtin_amdgcn_mfma_f32_16x16x32_bf16(af.v, b0, acc0, 0, 0, 0);
            acc1 = __builtin_amdgcn_mfma_f32_16x16x32_bf16(af.v, b1, acc1, 0, 0, 0);
        }
    }

    int crow = rowbase + (lane >> 4) * 4;
    int ccol = lane & 15;
#pragma unroll
    for (int r = 0; r < 4; ++r) {
        if (crow + r < NN)
            h1p[(size_t)(crow + r) * 16 + ccol] = pk2bf(acc0[r], acc1[r]);
    }
}

// ---------------- SWAR slice-scan: 4 nodes/thread via u32 words ----------------

__global__ __launch_bounds__(256) void k_xscan(unsigned* __restrict__ ghistw,
                                               int* __restrict__ cnt,
                                               float* __restrict__ dis,
                                               int* __restrict__ part) {
    __shared__ int red[256];
    int widx = blockIdx.x * 256 + threadIdx.x;
    int tot = 0;
    if (widx < XW) {
        unsigned s0 = 0, s1 = 0, s2 = 0, s3 = 0;
        unsigned* p = ghistw + widx;
#pragma unroll 4
        for (int m = 0; m < M_SL; ++m) {
            unsigned w = p[(size_t)m * XW];
            p[(size_t)m * XW] = s0 | (s1 << 8) | (s2 << 16) | (s3 << 24);
            s0 += w & 0xFFu; s1 += (w >> 8) & 0xFFu;
            s2 += (w >> 16) & 0xFFu; s3 += (w >> 24) & 0xFFu;
        }
        int c0 = widx * 4;
        *(int4*)(cnt + c0) = make_int4(s0, s1, s2, s3);
        *(float4*)(dis + c0) = make_float4(rsqrtf((float)s0 + 1.f), rsqrtf((float)s1 + 1.f),
                                           rsqrtf((float)s2 + 1.f), rsqrtf((float)s3 + 1.f));
        tot = s0 + s1 + s2 + s3;
    }
    red[threadIdx.x] = tot;
    __syncthreads();
    for (int st = 128; st > 0; st >>= 1) {
        if (threadIdx.x < st) red[threadIdx.x] += red[threadIdx.x + st];
        __syncthreads();
    }
    if (threadIdx.x == 0) part[blockIdx.x] = red[0];
}

// ---------------- off-scan (inline part-scan) ----------------

__global__ __launch_bounds__(1024) void k_scan_off(const int* __restrict__ cnt,
                                                   const int* __restrict__ part,
                                                   int* __restrict__ off) {
    __shared__ int s[1024];
    __shared__ int sp[128];
    int bid = blockIdx.x;
    if (threadIdx.x < 128) sp[threadIdx.x] = (threadIdx.x < XSB) ? part[threadIdx.x] : 0;
    __syncthreads();
    for (int st = 1; st < 128; st <<= 1) {
        int a = (threadIdx.x < 128 && threadIdx.x >= st) ? sp[threadIdx.x - st] : 0;
        __syncthreads();
        if (threadIdx.x < 128) sp[threadIdx.x] += a;
        __syncthreads();
    }
    int pbase = (bid == 0) ? 0 : sp[bid - 1];
    int i = bid * 1024 + threadIdx.x;
    int v = (i < NN) ? cnt[i] : 0;
    s[threadIdx.x] = v;
    __syncthreads();
    for (int st = 1; st < 1024; st <<= 1) {
        int a = (threadIdx.x >= st) ? s[threadIdx.x - st] : 0;
        __syncthreads();
        s[threadIdx.x] += a;
        __syncthreads();
    }
    if (i < NN) off[i] = pbase + s[threadIdx.x] - v;  // exclusive
    if (i == NN - 1) off[NN] = pbase + s[threadIdx.x];
}

// ---------------- CSR fill: atomic-free, slot = off[c] + ghist[m][c] + rank, 8 edges/thread ----------------

__global__ void k_fill(const int* __restrict__ row, const int* __restrict__ col,
                       const unsigned char* __restrict__ rank,
                       const int* __restrict__ off,
                       const unsigned char* __restrict__ ghist,
                       int* __restrict__ esrc) {
    int t = blockIdx.x * blockDim.x + threadIdx.x;
    if (t >= NE / 8) return;
#pragma unroll
    for (int qq = 0; qq < 2; ++qq) {
        int i = t * 2 + qq;  // quad index
        int m = i / QSL;     // slice
        int4 r4 = ((const int4*)row)[i];
        int4 c4 = ((const int4*)col)[i];
        uchar4 rk4 = ((const uchar4*)rank)[i];
        int rr[4] = {r4.x, r4.y, r4.z, r4.w};
        int cc[4] = {c4.x, c4.y, c4.z, c4.w};
        int rk[4] = {rk4.x, rk4.y, rk4.z, rk4.w};
        int o4[4], bp[4];
#pragma unroll
        for (int u = 0; u < 4; ++u) o4[u] = off[cc[u]];
#pragma unroll
        for (int u = 0; u < 4; ++u) bp[u] = ghist[(size_t)m * NN + cc[u]];
#pragma unroll
        for (int u = 0; u < 4; ++u) esrc[o4[u] + bp[u] + rk[u]] = rr[u];
    }
}

// ---------------- gather1 (uint2 lanes, dis-FMA) + relu + GEMM2: h2s = relu(...)@W2 * dis ----------------
// 32 nodes/block, 8 lanes/node; lane l owns words {2l, 2l+1} = features (2l, 2l+16, 2l+1, 2l+17)
// Reads unscaled permuted h1p; applies dis[r] as FMA weight per gathered row.

__global__ __launch_bounds__(256) void k_gather1g2(const int* __restrict__ off,
                                                   const int* __restrict__ esrc,
                                                   const unsigned* __restrict__ h1p,
                                                   const float* __restrict__ dis,
                                                   const float* __restrict__ b1,
                                                   const float* __restrict__ W2,
                                                   float* __restrict__ h2s) {
    __shared__ float w2l[FH * FC];       // 2 KB
    __shared__ float hrl[32][FH + 2];    // stride 34 (even): conflict-free, float2-aligned
    for (int i = threadIdx.x; i < FH * FC; i += 256) w2l[i] = W2[i];

    int ng = threadIdx.x >> 3;
    int l = threadIdx.x & 7;
    int g = blockIdx.x * 32 + ng;
    int s0 = off[g], s1 = off[g + 1];
    const uint2* hp = (const uint2*)h1p + l;  // row stride 8 uint2
    float a00 = 0.f, a01 = 0.f, a02 = 0.f, a03 = 0.f;
    float a10 = 0.f, a11 = 0.f, a12 = 0.f, a13 = 0.f;
    float a20 = 0.f, a21 = 0.f, a22 = 0.f, a23 = 0.f;
    float a30 = 0.f, a31 = 0.f, a32 = 0.f, a33 = 0.f;
    int i = s0;
    for (; i + 3 < s1; i += 4) {
        int r0 = esrc[i], r1 = esrc[i + 1], r2 = esrc[i + 2], r3 = esrc[i + 3];
        float d0 = dis[r0], d1 = dis[r1], d2 = dis[r2], d3 = dis[r3];
        uint2 w0 = hp[(size_t)r0 * 8];
        uint2 w1 = hp[(size_t)r1 * 8];
        uint2 w2 = hp[(size_t)r2 * 8];
        uint2 w3 = hp[(size_t)r3 * 8];
        a00 += d0 * bf2f((unsigned short)w0.x); a01 += d0 * bf2f((unsigned short)(w0.x >> 16));
        a02 += d0 * bf2f((unsigned short)w0.y); a03 += d0 * bf2f((unsigned short)(w0.y >> 16));
        a10 += d1 * bf2f((unsigned short)w1.x); a11 += d1 * bf2f((unsigned short)(w1.x >> 16));
        a12 += d1 * bf2f((unsigned short)w1.y); a13 += d1 * bf2f((unsigned short)(w1.y >> 16));
        a20 += d2 * bf2f((unsigned short)w2.x); a21 += d2 * bf2f((unsigned short)(w2.x >> 16));
        a22 += d2 * bf2f((unsigned short)w2.y); a23 += d2 * bf2f((unsigned short)(w2.y >> 16));
        a30 += d3 * bf2f((unsigned short)w3.x); a31 += d3 * bf2f((unsigned short)(w3.x >> 16));
        a32 += d3 * bf2f((unsigned short)w3.y); a33 += d3 * bf2f((unsigned short)(w3.y >> 16));
    }
    for (; i < s1; ++i) {
        int r = esrc[i];
        float d = dis[r];
        uint2 w = hp[(size_t)r * 8];
        a00 += d * bf2f((unsigned short)w.x); a01 += d * bf2f((unsigned short)(w.x >> 16));
        a02 += d * bf2f((unsigned short)w.y); a03 += d * bf2f((unsigned short)(w.y >> 16));
    }
    float dg = dis[g];
    uint2 ws = hp[(size_t)g * 8];
    float f0  = a00 + a10 + a20 + a30 + dg * bf2f((unsigned short)ws.x);        // feature 2l
    float f16 = a01 + a11 + a21 + a31 + dg * bf2f((unsigned short)(ws.x >> 16)); // 2l+16
    float f1  = a02 + a12 + a22 + a32 + dg * bf2f((unsigned short)ws.y);        // 2l+1
    float f17 = a03 + a13 + a23 + a33 + dg * bf2f((unsigned short)(ws.y >> 16)); // 2l+17
    float2 blo = ((const float2*)b1)[l];       // b1[2l], b1[2l+1]
    float2 bhi = ((const float2*)b1)[l + 8];   // b1[2l+16], b1[2l+17]
    float v0 = dg * f0 + blo.x;
    float v1 = dg * f1 + blo.y;
    float v16 = dg * f16 + bhi.x;
    float v17 = dg * f17 + bhi.y;
    *(float2*)&hrl[ng][2 * l] = make_float2(v0 > 0.f ? v0 : 0.f, v1 > 0.f ? v1 : 0.f);
    *(float2*)&hrl[ng][2 * l + 16] = make_float2(v16 > 0.f ? v16 : 0.f, v17 > 0.f ? v17 : 0.f);
    __syncthreads();

    int j = threadIdx.x & 15;
#pragma unroll
    for (int half = 0; half < 2; ++half) {
        int n2 = (threadIdx.x >> 4) + half * 16;
        int g2 = blockIdx.x * 32 + n2;
        float s = 0.0f;
#pragma unroll
        for (int k = 0; k < FH; ++k) s += hrl[n2][k] * w2l[k * FC + j];
        h2s[(size_t)g2 * FC + j] = s * dis[g2];
    }
}

// ---------------- gather2 (float4 lanes) + log_softmax -> out ----------------
// 64 nodes/block, 4 lanes/node, 4 classes/lane

__global__ __launch_bounds__(256) void k_gather2(const int* __restrict__ off,
                                                 const int* __restrict__ esrc,
                                                 const float* __restrict__ h2s,
                                                 const float* __restrict__ dis,
                                                 const float* __restrict__ b2,
                                                 float* __restrict__ out) {
    int ng = threadIdx.x >> 2;
    int l = threadIdx.x & 3;
    int g = blockIdx.x * 64 + ng;
    if (g >= NN) return;
    int s0 = off[g], s1 = off[g + 1];
    const float4* hp = (const float4*)h2s + l;  // row stride 4 float4
    float ax0 = 0.f, ay0 = 0.f, az0 = 0.f, aw0 = 0.f;
    float ax1 = 0.f, ay1 = 0.f, az1 = 0.f, aw1 = 0.f;
    float ax2 = 0.f, ay2 = 0.f, az2 = 0.f, aw2 = 0.f;
    float ax3 = 0.f, ay3 = 0.f, az3 = 0.f, aw3 = 0.f;
    int i = s0;
    for (; i + 3 < s1; i += 4) {
        int r0 = esrc[i], r1 = esrc[i + 1], r2 = esrc[i + 2], r3 = esrc[i + 3];
        float4 t0 = hp[(size_t)r0 * 4];
        float4 t1 = hp[(size_t)r1 * 4];
        float4 t2 = hp[(size_t)r2 * 4];
        float4 t3 = hp[(size_t)r3 * 4];
        ax0 += t0.x; ay0 += t0.y; az0 += t0.z; aw0 += t0.w;
        ax1 += t1.x; ay1 += t1.y; az1 += t1.z; aw1 += t1.w;
        ax2 += t2.x; ay2 += t2.y; az2 += t2.z; aw2 += t2.w;
        ax3 += t3.x; ay3 += t3.y; az3 += t3.z; aw3 += t3.w;
    }
    for (; i < s1; ++i) {
        float4 t = hp[(size_t)esrc[i] * 4];
        ax0 += t.x; ay0 += t.y; az0 += t.z; aw0 += t.w;
    }
    float4 ts = hp[(size_t)g * 4];
    float vx = ax0 + ax1 + ax2 + ax3 + ts.x;
    float vy = ay0 + ay1 + ay2 + ay3 + ts.y;
    float vz = az0 + az1 + az2 + az3 + ts.z;
    float vw = aw0 + aw1 + aw2 + aw3 + ts.w;
    float dg = dis[g];
    float4 bb = ((const float4*)b2)[l];
    vx = dg * vx + bb.x;
    vy = dg * vy + bb.y;
    vz = dg * vz + bb.z;
    vw = dg * vw + bb.w;
    float m = fmaxf(fmaxf(vx, vy), fmaxf(vz, vw));
#pragma unroll
    for (int o = 1; o < 4; o <<= 1) m = fmaxf(m, __shfl_xor(m, o, 4));
    float e = __expf(vx - m) + __expf(vy - m) + __expf(vz - m) + __expf(vw - m);
    float s = e;
#pragma unroll
    for (int o = 1; o < 4; o <<= 1) s += __shfl_xor(s, o, 4);
    float ls = m + logf(s);
    ((float4*)out)[(size_t)g * 4 + l] = make_float4(vx - ls, vy - ls, vz - ls, vw - ls);
}

extern "C" void kernel_launch(void* const* d_in, const int* in_sizes, int n_in,
                              void* d_out, int out_size, void* d_ws, size_t ws_size,
                              hipStream_t stream) {
    const float* x  = (const float*)d_in[0];
    const int*   ei = (const int*)d_in[1];
    const float* W1 = (const float*)d_in[2];
    const float* b1 = (const float*)d_in[3];
    const float* W2 = (const float*)d_in[4];
    const float* b2 = (const float*)d_in[5];
    float* out = (float*)d_out;

    const int* row = ei;
    const int* col = ei + NE;

    // workspace layout (int units, ~25 MB; all regions 16B-aligned)
    int* base = (int*)d_ws;
    unsigned char* ghist = (unsigned char*)base;            // M_SL*NN u8 = 800K ints
    unsigned char* rank  = ghist + (size_t)M_SL * NN;       // NE u8 = 400K ints
    int*   cnt   = base + 800000 + 400000;                  // NN
    int*   off   = cnt + NN;                                // NN+1 (pad 8)
    int*   part  = off + NN + 8;                            // 128
    float* dis   = (float*)(part + 128);                    // NN
    unsigned short* wbuf = (unsigned short*)(dis + NN);     // 16384 u16 = 8192 ints
    unsigned* h1p = (unsigned*)(wbuf + 16384);              // NN*16 u32 (1.6M ints) - live thru gather1
    float* h2s   = (float*)(h1p + (size_t)NN * 16);         // NN*FC f32 (1.6M ints)
    int*   esrc  = (int*)(h2s + (size_t)NN * FC);           // NE (1.6M ints)

    const int B = 256;

    k_prep<<<1, B, 0, stream>>>(W1, wbuf);
    k_hist_gemm1<<<NGB1 + NHB, B, 0, stream>>>(col, ghist, rank, x, wbuf, h1p);
    k_xscan<<<XSB, B, 0, stream>>>((unsigned*)ghist, cnt, dis, part);
    k_scan_off<<<SOS_NB, 1024, 0, stream>>>(cnt, part, off);
    k_fill<<<NCB2, B, 0, stream>>>(row, col, rank, off, ghist, esrc);
    k_gather1g2<<<NN / 32, B, 0, stream>>>(off, esrc, h1p, dis, b1, W2, h2s);
    k_gather2<<<(NN + 63) / 64, B, 0, stream>>>(off, esrc, h2s, dis, b2, out);
}

// Round 19
// 161.106 us; speedup vs baseline: 1.1419x; 1.0600x over previous
//
#include <hip/hip_runtime.h>
#include <hip/hip_bf16.h>

#define NN 100000
#define NE 1600000
#define FIN 512
#define FH 32
#define FC 16
#define NCB2 ((NE / 8 + 255) / 256)         // 782 fill blocks (8 edges/thread)
#define M_SL 64                             // edge slices
#define SLICE (NE / M_SL)                   // 25000 edges/slice
#define QSL (SLICE / 4)                     // 6250 quads/slice
#define PSZ 32768                           // nodes per pass (byte-packed 32 KB LDS)
#define NP ((NN + PSZ - 1) / PSZ)           // 4 passes
#define NHB (M_SL * NP)                     // 256 hist blocks
#define NGB1 ((NN + 63) / 64)               // 1563 MFMA gemm blocks
#define XW (NN / 4)                         // 25000 ghist words per slice
#define XSB ((XW + 255) / 256)              // 98 xscan blocks
#define SOS_NB 98                           // off-scan blocks (1024 nodes each)

typedef __attribute__((ext_vector_type(8))) short bf16x8;
typedef __attribute__((ext_vector_type(4))) float f32x4;

__device__ inline unsigned short f2bf(float f) {
    unsigned u = __float_as_uint(f);
    return (unsigned short)((u + 0x7FFFu + ((u >> 16) & 1u)) >> 16);  // RNE
}
__device__ inline float bf2f(unsigned short u) {
    return __uint_as_float(((unsigned)u) << 16);
}
__device__ inline unsigned pk2bf(float a, float b) {  // packed 2xbf16 via v_cvt_pk_bf16_f32
    __hip_bfloat162 p = __float22bfloat162_rn(make_float2(a, b));
    union { __hip_bfloat162 h; unsigned u; } c;
    c.h = p;
    return c.u;
}

// ---------------- prep: W1 -> bf16, pre-swizzled to B-fragment order ----------------

__global__ __launch_bounds__(256) void k_prep(const float* __restrict__ W1,
                                              unsigned short* __restrict__ wbuf) {
    for (int idx = threadIdx.x; idx < 16 * 2 * 64; idx += 256) {
        int s = idx >> 7;
        int t = (idx >> 6) & 1;
        int l = idx & 63;
        int k0 = s * 32 + (l >> 4) * 8;
        int c = t * 16 + (l & 15);
        bf16x8 w;
#pragma unroll
        for (int i = 0; i < 8; ++i) w[i] = (short)f2bf(W1[(size_t)(k0 + i) * FH + c]);
        *(bf16x8*)(wbuf + (size_t)idx * 8) = w;
    }
}

// ---------------- fused: byte-packed LDS hist (FIRST: long jobs start early)  +  MFMA GEMM1 ----------------
// blocks [0, NHB): hist pass p = hb/M_SL, slice m = hb%M_SL.
// blocks [NHB, NHB+NGB1): bf16 MFMA GEMM; h1p row = 16 u32 words, word w = (col w, col w+16).

__global__ __launch_bounds__(256) void k_hist_gemm1(const int* __restrict__ col,
                                                    unsigned char* __restrict__ ghist,
                                                    unsigned char* __restrict__ rank,
                                                    const float* __restrict__ x,
                                                    const unsigned short* __restrict__ wbuf,
                                                    unsigned* __restrict__ h1p) {
    __shared__ int sh[PSZ / 4];  // 32 KB; gemm path reuses as bf16 W store

    if (blockIdx.x < NHB) {
        int hb = blockIdx.x;
        int p = hb / M_SL;
        int m = hb % M_SL;
        int base = p * PSZ;
        int nb = min(PSZ, NN - base);
        int nw = (nb + 3) >> 2;
        unsigned* shw = (unsigned*)sh;
        for (int i = threadIdx.x; i < nw; i += 256) shw[i] = 0u;
        __syncthreads();
        const int4* c4p = (const int4*)(col + m * SLICE);
        for (int it = 0; it < (QSL + 255) / 256; ++it) {
            int q = it * 256 + threadIdx.x;
            if (q < QSL) {
                int4 c4 = c4p[q];
                int e = m * SLICE + q * 4;
                int cc[4] = {c4.x, c4.y, c4.z, c4.w};
#pragma unroll
                for (int u = 0; u < 4; ++u) {
                    int d = cc[u] - base;
                    if ((unsigned)d < (unsigned)nb) {
                        int sft = 8 * (d & 3);
                        unsigned old = atomicAdd(&shw[d >> 2], 1u << sft);
                        rank[e + u] = (unsigned char)((old >> sft) & 0xFFu);
                    }
                }
            }
        }
        __syncthreads();
        unsigned* gdst = (unsigned*)(ghist + (size_t)m * NN + base);  // 4B-aligned
        for (int i = threadIdx.x; i < nw; i += 256) gdst[i] = shw[i];
        return;
    }

    // ---- MFMA GEMM1 ----
    unsigned short* lb = (unsigned short*)sh;
    for (int i = threadIdx.x; i < 2048; i += 256)
        ((int4*)lb)[i] = ((const int4*)wbuf)[i];  // coalesced 32 KB stage
    __syncthreads();

    int wave = threadIdx.x >> 6;
    int lane = threadIdx.x & 63;
    int rowbase = (blockIdx.x - NHB) * 64 + wave * 16;
    int arow = rowbase + (lane & 15);
    int arowc = min(arow, NN - 1);
    int kgrp = (lane >> 4) * 8;

    f32x4 acc0 = {0.f, 0.f, 0.f, 0.f};
    f32x4 acc1 = {0.f, 0.f, 0.f, 0.f};
    const float* xrow = x + (size_t)arowc * FIN + kgrp;

    for (int sg = 0; sg < 16; sg += 4) {
        float4 av[8];
#pragma unroll
        for (int u = 0; u < 4; ++u) {
            av[2 * u]     = *(const float4*)(xrow + (sg + u) * 32);
            av[2 * u + 1] = *(const float4*)(xrow + (sg + u) * 32 + 4);
        }
#pragma unroll
        for (int u = 0; u < 4; ++u) {
            const float* s0 = (const float*)&av[2 * u];
            const float* s1 = (const float*)&av[2 * u + 1];
            union { bf16x8 v; unsigned w[4]; } af;
            af.w[0] = pk2bf(s0[0], s0[1]);
            af.w[1] = pk2bf(s0[2], s0[3]);
            af.w[2] = pk2bf(s1[0], s1[1]);
            af.w[3] = pk2bf(s1[2], s1[3]);
            int s = sg + u;
            bf16x8 b0 = *(const bf16x8*)(lb + ((size_t)(s * 2 + 0) * 64 + lane) * 8);
            bf16x8 b1 = *(const bf16x8*)(lb + ((size_t)(s * 2 + 1) * 64 + lane) * 8);
            acc0 = __builtin_amdgcn_mfma_f32_16x16x32_bf16(af.v, b0, acc0, 0, 0, 0);
            acc1 = __builtin_amdgcn_mfma_f32_16x16x32_bf16(af.v, b1, acc1, 0, 0, 0);
        }
    }

    int crow = rowbase + (lane >> 4) * 4;
    int ccol = lane & 15;
#pragma unroll
    for (int r = 0; r < 4; ++r) {
        if (crow + r < NN)
            h1p[(size_t)(crow + r) * 16 + ccol] = pk2bf(acc0[r], acc1[r]);
    }
}

// ---------------- SWAR slice-scan: 4 nodes/thread via u32 words ----------------

__global__ __launch_bounds__(256) void k_xscan(unsigned* __restrict__ ghistw,
                                               int* __restrict__ cnt,
                                               float* __restrict__ dis,
                                               int* __restrict__ part) {
    __shared__ int red[256];
    int widx = blockIdx.x * 256 + threadIdx.x;
    int tot = 0;
    if (widx < XW) {
        unsigned s0 = 0, s1 = 0, s2 = 0, s3 = 0;
        unsigned* p = ghistw + widx;
#pragma unroll 4
        for (int m = 0; m < M_SL; ++m) {
            unsigned w = p[(size_t)m * XW];
            p[(size_t)m * XW] = s0 | (s1 << 8) | (s2 << 16) | (s3 << 24);
            s0 += w & 0xFFu; s1 += (w >> 8) & 0xFFu;
            s2 += (w >> 16) & 0xFFu; s3 += (w >> 24) & 0xFFu;
        }
        int c0 = widx * 4;
        *(int4*)(cnt + c0) = make_int4(s0, s1, s2, s3);
        *(float4*)(dis + c0) = make_float4(rsqrtf((float)s0 + 1.f), rsqrtf((float)s1 + 1.f),
                                           rsqrtf((float)s2 + 1.f), rsqrtf((float)s3 + 1.f));
        tot = s0 + s1 + s2 + s3;
    }
    red[threadIdx.x] = tot;
    __syncthreads();
    for (int st = 128; st > 0; st >>= 1) {
        if (threadIdx.x < st) red[threadIdx.x] += red[threadIdx.x + st];
        __syncthreads();
    }
    if (threadIdx.x == 0) part[blockIdx.x] = red[0];
}

// ---------------- off-scan (inline part-scan) ----------------

__global__ __launch_bounds__(1024) void k_scan_off(const int* __restrict__ cnt,
                                                   const int* __restrict__ part,
                                                   int* __restrict__ off) {
    __shared__ int s[1024];
    __shared__ int sp[128];
    int bid = blockIdx.x;
    if (threadIdx.x < 128) sp[threadIdx.x] = (threadIdx.x < XSB) ? part[threadIdx.x] : 0;
    __syncthreads();
    for (int st = 1; st < 128; st <<= 1) {
        int a = (threadIdx.x < 128 && threadIdx.x >= st) ? sp[threadIdx.x - st] : 0;
        __syncthreads();
        if (threadIdx.x < 128) sp[threadIdx.x] += a;
        __syncthreads();
    }
    int pbase = (bid == 0) ? 0 : sp[bid - 1];
    int i = bid * 1024 + threadIdx.x;
    int v = (i < NN) ? cnt[i] : 0;
    s[threadIdx.x] = v;
    __syncthreads();
    for (int st = 1; st < 1024; st <<= 1) {
        int a = (threadIdx.x >= st) ? s[threadIdx.x - st] : 0;
        __syncthreads();
        s[threadIdx.x] += a;
        __syncthreads();
    }
    if (i < NN) off[i] = pbase + s[threadIdx.x] - v;  // exclusive
    if (i == NN - 1) off[NN] = pbase + s[threadIdx.x];
}

// ---------------- CSR fill: atomic-free, slot = off[c] + ghist[m][c] + rank, 8 edges/thread ----------------

__global__ void k_fill(const int* __restrict__ row, const int* __restrict__ col,
                       const unsigned char* __restrict__ rank,
                       const int* __restrict__ off,
                       const unsigned char* __restrict__ ghist,
                       int* __restrict__ esrc) {
    int t = blockIdx.x * blockDim.x + threadIdx.x;
    if (t >= NE / 8) return;
#pragma unroll
    for (int qq = 0; qq < 2; ++qq) {
        int i = t * 2 + qq;  // quad index
        int m = i / QSL;     // slice
        int4 r4 = ((const int4*)row)[i];
        int4 c4 = ((const int4*)col)[i];
        uchar4 rk4 = ((const uchar4*)rank)[i];
        int rr[4] = {r4.x, r4.y, r4.z, r4.w};
        int cc[4] = {c4.x, c4.y, c4.z, c4.w};
        int rk[4] = {rk4.x, rk4.y, rk4.z, rk4.w};
        int o4[4], bp[4];
#pragma unroll
        for (int u = 0; u < 4; ++u) o4[u] = off[cc[u]];
#pragma unroll
        for (int u = 0; u < 4; ++u) bp[u] = ghist[(size_t)m * NN + cc[u]];
#pragma unroll
        for (int u = 0; u < 4; ++u) esrc[o4[u] + bp[u] + rk[u]] = rr[u];
    }
}

// ---------------- gather1 (uint2 lanes, dis-FMA) + relu + GEMM2: h2s = relu(...)@W2 * dis ----------------
// 32 nodes/block, 8 lanes/node; lane l owns words {2l, 2l+1} = features (2l, 2l+16, 2l+1, 2l+17)

__global__ __launch_bounds__(256) void k_gather1g2(const int* __restrict__ off,
                                                   const int* __restrict__ esrc,
                                                   const unsigned* __restrict__ h1p,
                                                   const float* __restrict__ dis,
                                                   const float* __restrict__ b1,
                                                   const float* __restrict__ W2,
                                                   float* __restrict__ h2s) {
    __shared__ float w2l[FH * FC];       // 2 KB
    __shared__ float hrl[32][FH + 2];    // stride 34 (even): conflict-free, float2-aligned
    for (int i = threadIdx.x; i < FH * FC; i += 256) w2l[i] = W2[i];

    int ng = threadIdx.x >> 3;
    int l = threadIdx.x & 7;
    int g = blockIdx.x * 32 + ng;
    int s0 = off[g], s1 = off[g + 1];
    const uint2* hp = (const uint2*)h1p + l;  // row stride 8 uint2
    float a00 = 0.f, a01 = 0.f, a02 = 0.f, a03 = 0.f;
    float a10 = 0.f, a11 = 0.f, a12 = 0.f, a13 = 0.f;
    float a20 = 0.f, a21 = 0.f, a22 = 0.f, a23 = 0.f;
    float a30 = 0.f, a31 = 0.f, a32 = 0.f, a33 = 0.f;
    int i = s0;
    for (; i + 3 < s1; i += 4) {
        int r0 = esrc[i], r1 = esrc[i + 1], r2 = esrc[i + 2], r3 = esrc[i + 3];
        float d0 = dis[r0], d1 = dis[r1], d2 = dis[r2], d3 = dis[r3];
        uint2 w0 = hp[(size_t)r0 * 8];
        uint2 w1 = hp[(size_t)r1 * 8];
        uint2 w2 = hp[(size_t)r2 * 8];
        uint2 w3 = hp[(size_t)r3 * 8];
        a00 += d0 * bf2f((unsigned short)w0.x); a01 += d0 * bf2f((unsigned short)(w0.x >> 16));
        a02 += d0 * bf2f((unsigned short)w0.y); a03 += d0 * bf2f((unsigned short)(w0.y >> 16));
        a10 += d1 * bf2f((unsigned short)w1.x); a11 += d1 * bf2f((unsigned short)(w1.x >> 16));
        a12 += d1 * bf2f((unsigned short)w1.y); a13 += d1 * bf2f((unsigned short)(w1.y >> 16));
        a20 += d2 * bf2f((unsigned short)w2.x); a21 += d2 * bf2f((unsigned short)(w2.x >> 16));
        a22 += d2 * bf2f((unsigned short)w2.y); a23 += d2 * bf2f((unsigned short)(w2.y >> 16));
        a30 += d3 * bf2f((unsigned short)w3.x); a31 += d3 * bf2f((unsigned short)(w3.x >> 16));
        a32 += d3 * bf2f((unsigned short)w3.y); a33 += d3 * bf2f((unsigned short)(w3.y >> 16));
    }
    for (; i < s1; ++i) {
        int r = esrc[i];
        float d = dis[r];
        uint2 w = hp[(size_t)r * 8];
        a00 += d * bf2f((unsigned short)w.x); a01 += d * bf2f((unsigned short)(w.x >> 16));
        a02 += d * bf2f((unsigned short)w.y); a03 += d * bf2f((unsigned short)(w.y >> 16));
    }
    float dg = dis[g];
    uint2 ws = hp[(size_t)g * 8];
    float f0  = a00 + a10 + a20 + a30 + dg * bf2f((unsigned short)ws.x);        // feature 2l
    float f16 = a01 + a11 + a21 + a31 + dg * bf2f((unsigned short)(ws.x >> 16)); // 2l+16
    float f1  = a02 + a12 + a22 + a32 + dg * bf2f((unsigned short)ws.y);        // 2l+1
    float f17 = a03 + a13 + a23 + a33 + dg * bf2f((unsigned short)(ws.y >> 16)); // 2l+17
    float2 blo = ((const float2*)b1)[l];       // b1[2l], b1[2l+1]
    float2 bhi = ((const float2*)b1)[l + 8];   // b1[2l+16], b1[2l+17]
    float v0 = dg * f0 + blo.x;
    float v1 = dg * f1 + blo.y;
    float v16 = dg * f16 + bhi.x;
    float v17 = dg * f17 + bhi.y;
    *(float2*)&hrl[ng][2 * l] = make_float2(v0 > 0.f ? v0 : 0.f, v1 > 0.f ? v1 : 0.f);
    *(float2*)&hrl[ng][2 * l + 16] = make_float2(v16 > 0.f ? v16 : 0.f, v17 > 0.f ? v17 : 0.f);
    __syncthreads();

    int j = threadIdx.x & 15;
#pragma unroll
    for (int half = 0; half < 2; ++half) {
        int n2 = (threadIdx.x >> 4) + half * 16;
        int g2 = blockIdx.x * 32 + n2;
        float s = 0.0f;
#pragma unroll
        for (int k = 0; k < FH; ++k) s += hrl[n2][k] * w2l[k * FC + j];
        h2s[(size_t)g2 * FC + j] = s * dis[g2];
    }
}

// ---------------- gather2 (float4 lanes) + log_softmax -> out ----------------
// 64 nodes/block, 4 lanes/node, 4 classes/lane

__global__ __launch_bounds__(256) void k_gather2(const int* __restrict__ off,
                                                 const int* __restrict__ esrc,
                                                 const float* __restrict__ h2s,
                                                 const float* __restrict__ dis,
                                                 const float* __restrict__ b2,
                                                 float* __restrict__ out) {
    int ng = threadIdx.x >> 2;
    int l = threadIdx.x & 3;
    int g = blockIdx.x * 64 + ng;
    if (g >= NN) return;
    int s0 = off[g], s1 = off[g + 1];
    const float4* hp = (const float4*)h2s + l;  // row stride 4 float4
    float ax0 = 0.f, ay0 = 0.f, az0 = 0.f, aw0 = 0.f;
    float ax1 = 0.f, ay1 = 0.f, az1 = 0.f, aw1 = 0.f;
    float ax2 = 0.f, ay2 = 0.f, az2 = 0.f, aw2 = 0.f;
    float ax3 = 0.f, ay3 = 0.f, az3 = 0.f, aw3 = 0.f;
    int i = s0;
    for (; i + 3 < s1; i += 4) {
        int r0 = esrc[i], r1 = esrc[i + 1], r2 = esrc[i + 2], r3 = esrc[i + 3];
        float4 t0 = hp[(size_t)r0 * 4];
        float4 t1 = hp[(size_t)r1 * 4];
        float4 t2 = hp[(size_t)r2 * 4];
        float4 t3 = hp[(size_t)r3 * 4];
        ax0 += t0.x; ay0 += t0.y; az0 += t0.z; aw0 += t0.w;
        ax1 += t1.x; ay1 += t1.y; az1 += t1.z; aw1 += t1.w;
        ax2 += t2.x; ay2 += t2.y; az2 += t2.z; aw2 += t2.w;
        ax3 += t3.x; ay3 += t3.y; az3 += t3.z; aw3 += t3.w;
    }
    for (; i < s1; ++i) {
        float4 t = hp[(size_t)esrc[i] * 4];
        ax0 += t.x; ay0 += t.y; az0 += t.z; aw0 += t.w;
    }
    float4 ts = hp[(size_t)g * 4];
    float vx = ax0 + ax1 + ax2 + ax3 + ts.x;
    float vy = ay0 + ay1 + ay2 + ay3 + ts.y;
    float vz = az0 + az1 + az2 + az3 + ts.z;
    float vw = aw0 + aw1 + aw2 + aw3 + ts.w;
    float dg = dis[g];
    float4 bb = ((const float4*)b2)[l];
    vx = dg * vx + bb.x;
    vy = dg * vy + bb.y;
    vz = dg * vz + bb.z;
    vw = dg * vw + bb.w;
    float m = fmaxf(fmaxf(vx, vy), fmaxf(vz, vw));
#pragma unroll
    for (int o = 1; o < 4; o <<= 1) m = fmaxf(m, __shfl_xor(m, o, 4));
    float e = __expf(vx - m) + __expf(vy - m) + __expf(vz - m) + __expf(vw - m);
    float s = e;
#pragma unroll
    for (int o = 1; o < 4; o <<= 1) s += __shfl_xor(s, o, 4);
    float ls = m + logf(s);
    ((float4*)out)[(size_t)g * 4 + l] = make_float4(vx - ls, vy - ls, vz - ls, vw - ls);
}

extern "C" void kernel_launch(void* const* d_in, const int* in_sizes, int n_in,
                              void* d_out, int out_size, void* d_ws, size_t ws_size,
                              hipStream_t stream) {
    const float* x  = (const float*)d_in[0];
    const int*   ei = (const int*)d_in[1];
    const float* W1 = (const float*)d_in[2];
    const float* b1 = (const float*)d_in[3];
    const float* W2 = (const float*)d_in[4];
    const float* b2 = (const float*)d_in[5];
    float* out = (float*)d_out;

    const int* row = ei;
    const int* col = ei + NE;

    // workspace layout (int units, ~28 MB; all regions 16B-aligned)
    int* base = (int*)d_ws;
    unsigned char* ghist = (unsigned char*)base;            // M_SL*NN u8 = 1.6M ints
    unsigned char* rank  = ghist + (size_t)M_SL * NN;       // NE u8 = 400K ints
    int*   cnt   = base + 1600000 + 400000;                 // NN
    int*   off   = cnt + NN;                                // NN+1 (pad 8)
    int*   part  = off + NN + 8;                            // 128
    float* dis   = (float*)(part + 128);                    // NN
    unsigned short* wbuf = (unsigned short*)(dis + NN);     // 16384 u16 = 8192 ints
    unsigned* h1p = (unsigned*)(wbuf + 16384);              // NN*16 u32 (1.6M ints) - live thru gather1
    float* h2s   = (float*)(h1p + (size_t)NN * 16);         // NN*FC f32 (1.6M ints)
    int*   esrc  = (int*)(h2s + (size_t)NN * FC);           // NE (1.6M ints)

    const int B = 256;

    k_prep<<<1, B, 0, stream>>>(W1, wbuf);
    k_hist_gemm1<<<NHB + NGB1, B, 0, stream>>>(col, ghist, rank, x, wbuf, h1p);
    k_xscan<<<XSB, B, 0, stream>>>((unsigned*)ghist, cnt, dis, part);
    k_scan_off<<<SOS_NB, 1024, 0, stream>>>(cnt, part, off);
    k_fill<<<NCB2, B, 0, stream>>>(row, col, rank, off, ghist, esrc);
    k_gather1g2<<<NN / 32, B, 0, stream>>>(off, esrc, h1p, dis, b1, W2, h2s);
    k_gather2<<<(NN + 63) / 64, B, 0, stream>>>(off, esrc, h2s, dis, b2, out);
}